// Round 2
// baseline (1259.229 us; speedup 1.0000x reference)
//
#include <hip/hip_runtime.h>

// Langevin dynamics with bit-exact reproduction of JAX Threefry-2x32 RNG,
// *partitionable* semantics (JAX >= 0.4.30 default):
//   split(key, n):  keys[t]  = threefry2x32(key, counter=(0, t))  -> (o0, o1)
//   random_bits32:  bits[i]  = fold_in via XOR: o0 ^ o1 of
//                              threefry2x32(key_t, counter=(0, i))
// Each thread owns elements (j, j+H); state lives in registers for all
// n_steps; only the initial load and final store touch HBM.

#define TF_ROUND(x0, x1, R)                                   \
  {                                                           \
    x0 += x1;                                                 \
    x1 = ((x1 << (R)) | (x1 >> (32 - (R))));                  \
    x1 ^= x0;                                                 \
  }

__device__ __forceinline__ void tf2x32(unsigned k0, unsigned k1,
                                       unsigned c0, unsigned c1,
                                       unsigned& o0, unsigned& o1) {
  const unsigned k2 = k0 ^ k1 ^ 0x1BD11BDAu;
  unsigned x0 = c0 + k0;
  unsigned x1 = c1 + k1;
  TF_ROUND(x0, x1, 13) TF_ROUND(x0, x1, 15) TF_ROUND(x0, x1, 26) TF_ROUND(x0, x1, 6)
  x0 += k1; x1 += k2 + 1u;
  TF_ROUND(x0, x1, 17) TF_ROUND(x0, x1, 29) TF_ROUND(x0, x1, 16) TF_ROUND(x0, x1, 24)
  x0 += k2; x1 += k0 + 2u;
  TF_ROUND(x0, x1, 13) TF_ROUND(x0, x1, 15) TF_ROUND(x0, x1, 26) TF_ROUND(x0, x1, 6)
  x0 += k0; x1 += k1 + 3u;
  TF_ROUND(x0, x1, 17) TF_ROUND(x0, x1, 29) TF_ROUND(x0, x1, 16) TF_ROUND(x0, x1, 24)
  x0 += k1; x1 += k2 + 4u;
  TF_ROUND(x0, x1, 13) TF_ROUND(x0, x1, 15) TF_ROUND(x0, x1, 26) TF_ROUND(x0, x1, 6)
  x0 += k2; x1 += k0 + 5u;
  o0 = x0;
  o1 = x1;
}

// XLA ErfInvImpl (32-bit) — Giles polynomial, exact coefficients from
// xla/client/lib/math.cc so our noise matches the JAX reference.
__device__ __forceinline__ float erfinv_f32(float x) {
  float w = -log1pf(-x * x);
  float p;
  if (w < 5.0f) {
    w = w - 2.5f;
    p = 2.81022636e-08f;
    p = fmaf(p, w, 3.43273939e-07f);
    p = fmaf(p, w, -3.5233877e-06f);
    p = fmaf(p, w, -4.39150654e-06f);
    p = fmaf(p, w, 0.00021858087f);
    p = fmaf(p, w, -0.00125372503f);
    p = fmaf(p, w, -0.00417768164f);
    p = fmaf(p, w, 0.246640727f);
    p = fmaf(p, w, 1.50140941f);
  } else {
    w = sqrtf(w) - 3.0f;
    p = -0.000200214257f;
    p = fmaf(p, w, 0.000100950558f);
    p = fmaf(p, w, 0.00134934322f);
    p = fmaf(p, w, -0.00367342844f);
    p = fmaf(p, w, 0.00573950773f);
    p = fmaf(p, w, -0.0076224613f);
    p = fmaf(p, w, 0.00943887047f);
    p = fmaf(p, w, 1.00167406f);
    p = fmaf(p, w, 2.83297682f);
  }
  return p * x;
}

// JAX uniform(-0.99999994, 1.0) -> sqrt(2)*erfinv(u).
// (maxval-minval) rounds to exactly 2.0f (tie-to-even); f*2 is exact,
// so fmaf == XLA's mul-then-add bit-for-bit.
__device__ __forceinline__ float bits_to_normal(unsigned bits) {
  const float f = __uint_as_float((bits >> 9) | 0x3F800000u) - 1.0f;  // [0,1)
  const float lo = -0.99999994f;  // nextafter(-1, 0) in f32
  const float u = fmaxf(lo, fmaf(f, 2.0f, lo));
  return __uint_as_float(0x3FB504F3u) * erfinv_f32(u);  // f32(sqrt(2)) * erfinv
}

__global__ __launch_bounds__(256) void langevin_tf(
    const float* __restrict__ x0, const float* __restrict__ bias,
    const int* __restrict__ nsteps_p, float* __restrict__ out,
    int H, int ndim) {
  // --- key table: jax.random.split(key(1), n_steps), partitionable ---
  // keys[t] = threefry2x32(key=(0,1), counter=(0, t)) stacked on last axis.
  __shared__ unsigned skeys[2048];  // supports n_steps <= 1024
  const int n_steps = nsteps_p[0];
  for (int l = (int)threadIdx.x; l < n_steps; l += (int)blockDim.x) {
    unsigned o0, o1;
    tf2x32(0u, 1u, 0u, (unsigned)l, o0, o1);
    skeys[2 * l] = o0;
    skeys[2 * l + 1] = o1;
  }
  __syncthreads();

  const int j = (int)(blockIdx.x * blockDim.x + threadIdx.x);
  if (j >= H) return;
  const unsigned ca = (unsigned)j;
  const unsigned cb = (unsigned)(j + H);
  float xa = x0[j];
  float xb = x0[j + H];
  const float ba = bias[j % ndim];
  const float bb = bias[(j + H) % ndim];

  for (int t = 0; t < n_steps; ++t) {
    const unsigned k0 = skeys[2 * t];      // uniform addr -> LDS broadcast
    const unsigned k1 = skeys[2 * t + 1];
    unsigned a0, a1, b0, b1;
    tf2x32(k0, k1, 0u, ca, a0, a1);        // element j:   counter (0, j)
    tf2x32(k0, k1, 0u, cb, b0, b1);        // element j+H: counter (0, j+H)
    const float na = bits_to_normal(a0 ^ a1);  // partitionable 32-bit fold
    const float nb = bits_to_normal(b0 ^ b1);
    // grad = 2*J2*x + 4*J4*x^3 + b = -2x + ((2x)*x)*x + b  (ref assoc. order)
    const float ga = -2.0f * xa + ((2.0f * xa) * xa) * xa + ba;
    xa = (xa - ga * 0.01f) + na * 0.1f;
    const float gb = -2.0f * xb + ((2.0f * xb) * xb) * xb + bb;
    xb = (xb - gb * 0.01f) + nb * 0.1f;
  }
  out[j] = xa;
  out[j + H] = xb;
}

extern "C" void kernel_launch(void* const* d_in, const int* in_sizes, int n_in,
                              void* d_out, int out_size, void* d_ws, size_t ws_size,
                              hipStream_t stream) {
  (void)n_in; (void)d_ws; (void)ws_size; (void)out_size;
  const float* x0 = (const float*)d_in[0];
  const float* b = (const float*)d_in[1];
  const int* ns = (const int*)d_in[2];
  float* out = (float*)d_out;

  const int n = in_sizes[0];       // 2048*256 = 524288
  const int ndim = in_sizes[1];    // 256
  const int H = n / 2;             // one thread per element pair (j, j+H)
  const int block = 256;
  const int grid = (H + block - 1) / block;
  hipLaunchKernelGGL(langevin_tf, dim3(grid), dim3(block), 0, stream,
                     x0, b, ns, out, H, ndim);
}

// Round 3
// 607.878 us; speedup vs baseline: 2.0715x; 2.0715x over previous
//
#include <hip/hip_runtime.h>

// Langevin dynamics, bit-matched to JAX Threefry-2x32 *partitionable* RNG:
//   split(key, n):  keys[t] = threefry2x32(key=(0,1), counter=(0, t))
//   random_bits32:  bits[i] = o0 ^ o1 of threefry2x32(key_t, counter=(0, i))
// One element per thread (grid 2048 blocks -> 32 waves/CU). Key for step t+1
// is prefetched from LDS while step t computes; unroll-2 interleaves two
// independent threefry chains (step t+1's noise has no dep on step t's x).

#define TF_ROUND(x0, x1, R)                                   \
  {                                                           \
    x0 += x1;                                                 \
    x1 = ((x1 << (R)) | (x1 >> (32 - (R))));                  \
    x1 ^= x0;                                                 \
  }

__device__ __forceinline__ void tf2x32(unsigned k0, unsigned k1,
                                       unsigned c0, unsigned c1,
                                       unsigned& o0, unsigned& o1) {
  const unsigned k2 = k0 ^ k1 ^ 0x1BD11BDAu;
  unsigned x0 = c0 + k0;
  unsigned x1 = c1 + k1;
  TF_ROUND(x0, x1, 13) TF_ROUND(x0, x1, 15) TF_ROUND(x0, x1, 26) TF_ROUND(x0, x1, 6)
  x0 += k1; x1 += k2 + 1u;
  TF_ROUND(x0, x1, 17) TF_ROUND(x0, x1, 29) TF_ROUND(x0, x1, 16) TF_ROUND(x0, x1, 24)
  x0 += k2; x1 += k0 + 2u;
  TF_ROUND(x0, x1, 13) TF_ROUND(x0, x1, 15) TF_ROUND(x0, x1, 26) TF_ROUND(x0, x1, 6)
  x0 += k0; x1 += k1 + 3u;
  TF_ROUND(x0, x1, 17) TF_ROUND(x0, x1, 29) TF_ROUND(x0, x1, 16) TF_ROUND(x0, x1, 24)
  x0 += k1; x1 += k2 + 4u;
  TF_ROUND(x0, x1, 13) TF_ROUND(x0, x1, 15) TF_ROUND(x0, x1, 26) TF_ROUND(x0, x1, 6)
  x0 += k2; x1 += k0 + 5u;
  o0 = x0;
  o1 = x1;
}

// uniform(-0.99999994, 1) -> sqrt(2)*erfinv(u), XLA ErfInv32 (Giles) poly.
// log1p(-u*u) replaced by 1-ulp-class hw path: for m>=0.5 (1-m) is
// Sterbenz-exact; for m<0.5 abs err in w <= 2^-24; v_log_f32 <= 1 ulp.
// Net w mismatch vs XLA ~2 ulp — same scale as OCML log1pf mismatch.
__device__ __forceinline__ float bits_to_normal(unsigned bits) {
  const float f = __uint_as_float((bits >> 9) | 0x3F800000u) - 1.0f;  // [0,1)
  const float lo = -0.99999994f;              // nextafter(-1, 0)
  const float u = fmaf(f, 2.0f, lo);          // == clamped form, proven
  const float m = u * u;                      // rounded first, as XLA does
  const float t = 1.0f - m;
  const float l = __log2f(t);                 // v_log_f32
  // w = -(l * ln2), extended split: ln2 = HI + LO
  float w = fmaf(l, -0.69314718246459961f, l * 1.9046543e-09f);
  float p;
  if (w < 5.0f) {
    w = w - 2.5f;
    p = 2.81022636e-08f;
    p = fmaf(p, w, 3.43273939e-07f);
    p = fmaf(p, w, -3.5233877e-06f);
    p = fmaf(p, w, -4.39150654e-06f);
    p = fmaf(p, w, 0.00021858087f);
    p = fmaf(p, w, -0.00125372503f);
    p = fmaf(p, w, -0.00417768164f);
    p = fmaf(p, w, 0.246640727f);
    p = fmaf(p, w, 1.50140941f);
  } else {
    w = sqrtf(w) - 3.0f;
    p = -0.000200214257f;
    p = fmaf(p, w, 0.000100950558f);
    p = fmaf(p, w, 0.00134934322f);
    p = fmaf(p, w, -0.00367342844f);
    p = fmaf(p, w, 0.00573950773f);
    p = fmaf(p, w, -0.0076224613f);
    p = fmaf(p, w, 0.00943887047f);
    p = fmaf(p, w, 1.00167406f);
    p = fmaf(p, w, 2.83297682f);
  }
  return __uint_as_float(0x3FB504F3u) * (p * u);  // f32(sqrt(2)) * erfinv(u)
}

__global__ __launch_bounds__(256, 8) void langevin_tf(
    const float* __restrict__ x0, const float* __restrict__ bias,
    const int* __restrict__ nsteps_p, float* __restrict__ out,
    int N, int ndim) {
  // key table: jax.random.split(key(1), n_steps), partitionable semantics
  __shared__ uint2 skeys[1025];  // +1: prefetch reads skeys[n_steps] (unused)
  const int n_steps = __builtin_amdgcn_readfirstlane(nsteps_p[0]);
  const int nfill = n_steps < 1024 ? n_steps : 1024;
  for (int l = (int)threadIdx.x; l < nfill; l += (int)blockDim.x) {
    unsigned o0, o1;
    tf2x32(0u, 1u, 0u, (unsigned)l, o0, o1);
    skeys[l] = make_uint2(o0, o1);
  }
  __syncthreads();

  const int j = (int)(blockIdx.x * blockDim.x + threadIdx.x);
  if (j >= N) return;
  const unsigned cj = (unsigned)j;
  float x = x0[j];
  const float b = bias[j % ndim];

  uint2 kc = skeys[0];
#pragma unroll 2
  for (int t = 0; t < n_steps; ++t) {
    const uint2 kn = skeys[t + 1];  // prefetch next step's key (ds_read_b64)
    unsigned r0, r1;
    tf2x32(kc.x, kc.y, 0u, cj, r0, r1);     // counter (0, j)
    const float nz = bits_to_normal(r0 ^ r1);  // partitionable 32-bit fold
    // grad = 2*J2*x + 4*J4*x^3 + b = -2x + ((2x)*x)*x + b  (ref assoc. order)
    const float g = -2.0f * x + ((2.0f * x) * x) * x + b;
    x = (x - g * 0.01f) + nz * 0.1f;
    kc = kn;
  }
  out[j] = x;
}

extern "C" void kernel_launch(void* const* d_in, const int* in_sizes, int n_in,
                              void* d_out, int out_size, void* d_ws, size_t ws_size,
                              hipStream_t stream) {
  (void)n_in; (void)d_ws; (void)ws_size; (void)out_size;
  const float* x0 = (const float*)d_in[0];
  const float* b = (const float*)d_in[1];
  const int* ns = (const int*)d_in[2];
  float* out = (float*)d_out;

  const int n = in_sizes[0];     // 2048*256 = 524288
  const int ndim = in_sizes[1];  // 256
  const int block = 256;
  const int grid = (n + block - 1) / block;  // 2048 blocks -> 8/CU, 32 waves/CU
  hipLaunchKernelGGL(langevin_tf, dim3(grid), dim3(block), 0, stream,
                     x0, b, ns, out, n, ndim);
}

// Round 4
// 601.876 us; speedup vs baseline: 2.0922x; 1.0100x over previous
//
#include <hip/hip_runtime.h>

// Langevin dynamics, bit-matched to JAX Threefry-2x32 *partitionable* RNG:
//   split(key, n):  keys[t] = threefry2x32(key=(0,1), counter=(0, t))
//   random_bits32:  bits[i] = o0 ^ o1 of threefry2x32(key_t, counter=(0, i))
// One element per thread (2048 blocks -> 32 waves/CU). Per-step key schedule
// pre-expanded to 8 words in LDS. Loop body = TWO steps, branchless erfinv,
// single basic block so the scheduler interleaves the two independent
// threefry chains with the short serial x-update chain.

__device__ __forceinline__ void tf_r4a(unsigned& x0, unsigned& x1) {
  x0 += x1; x1 = (x1 << 13) | (x1 >> 19); x1 ^= x0;
  x0 += x1; x1 = (x1 << 15) | (x1 >> 17); x1 ^= x0;
  x0 += x1; x1 = (x1 << 26) | (x1 >> 6);  x1 ^= x0;
  x0 += x1; x1 = (x1 << 6)  | (x1 >> 26); x1 ^= x0;
}
__device__ __forceinline__ void tf_r4b(unsigned& x0, unsigned& x1) {
  x0 += x1; x1 = (x1 << 17) | (x1 >> 15); x1 ^= x0;
  x0 += x1; x1 = (x1 << 29) | (x1 >> 3);  x1 ^= x0;
  x0 += x1; x1 = (x1 << 16) | (x1 >> 16); x1 ^= x0;
  x0 += x1; x1 = (x1 << 24) | (x1 >> 8);  x1 ^= x0;
}

__device__ __forceinline__ void tf2x32(unsigned k0, unsigned k1,
                                       unsigned c0, unsigned c1,
                                       unsigned& o0, unsigned& o1) {
  const unsigned k2 = k0 ^ k1 ^ 0x1BD11BDAu;
  unsigned x0 = c0 + k0, x1 = c1 + k1;
  tf_r4a(x0, x1); x0 += k1; x1 += k2 + 1u;
  tf_r4b(x0, x1); x0 += k2; x1 += k0 + 2u;
  tf_r4a(x0, x1); x0 += k0; x1 += k1 + 3u;
  tf_r4b(x0, x1); x0 += k1; x1 += k2 + 4u;
  tf_r4a(x0, x1); x0 += k2; x1 += k0 + 5u;
  o0 = x0; o1 = x1;
}

// threefry with pre-expanded key schedule w[0..7] =
// {k0, k1, k2, k2+1, k0+2, k1+3, k2+4, k0+5}; counter (0, c1); returns o0^o1.
__device__ __forceinline__ unsigned tf_fold(const unsigned w[8], unsigned c1) {
  unsigned x0 = w[0], x1 = c1 + w[1];
  tf_r4a(x0, x1); x0 += w[1]; x1 += w[3];
  tf_r4b(x0, x1); x0 += w[2]; x1 += w[4];
  tf_r4a(x0, x1); x0 += w[0]; x1 += w[5];
  tf_r4b(x0, x1); x0 += w[1]; x1 += w[6];
  tf_r4a(x0, x1); x0 += w[2]; x1 += w[7];
  return x0 ^ x1;
}

// uniform(-0.99999994, 1) -> sqrt(2)*erfinv(u), XLA ErfInv32 (Giles) poly.
// Branchless: coefficient pairs selected by v_cndmask so the whole noise
// computation is one basic block. Values identical to the branchy version
// for the dominant w<5 class; tail class uses 1-ulp v_sqrt (negligible).
__device__ __forceinline__ float bits_to_normal(unsigned bits) {
  const float f = __uint_as_float((bits >> 9) | 0x3F800000u) - 1.0f;  // [0,1)
  const float u = fmaf(f, 2.0f, -0.99999994f);   // uniform(lo, 1)
  const float m = u * u;
  const float l = __log2f(1.0f - m);             // v_log_f32
  // w = -log1p(-m) = -(l*ln2); ln2 split HI+LO for ~2-ulp agreement w/ XLA
  const float w = fmaf(l, -0.69314718246459961f, l * 1.9046543e-09f);
  const bool s = w < 5.0f;
  const float za = w - 2.5f;
  const float zb = __builtin_amdgcn_sqrtf(w) - 3.0f;
  const float z = s ? za : zb;
  float p =          s ? 2.81022636e-08f  : -0.000200214257f;
  p = fmaf(p, z,     s ? 3.43273939e-07f  :  0.000100950558f);
  p = fmaf(p, z,     s ? -3.5233877e-06f  :  0.00134934322f);
  p = fmaf(p, z,     s ? -4.39150654e-06f : -0.00367342844f);
  p = fmaf(p, z,     s ? 0.00021858087f   :  0.00573950773f);
  p = fmaf(p, z,     s ? -0.00125372503f  : -0.0076224613f);
  p = fmaf(p, z,     s ? -0.00417768164f  :  0.00943887047f);
  p = fmaf(p, z,     s ? 0.246640727f     :  1.00167406f);
  p = fmaf(p, z,     s ? 1.50140941f      :  2.83297682f);
  return __uint_as_float(0x3FB504F3u) * (p * u);  // f32(sqrt(2)) * erfinv(u)
}

__global__ __launch_bounds__(256, 8) void langevin_tf(
    const float* __restrict__ x0p, const float* __restrict__ bias,
    const int* __restrict__ nsteps_p, float* __restrict__ out,
    int N, int ndim) {
  // Pre-expanded key schedule: 8 words per step, 16 KB for 512 steps.
  __shared__ __align__(16) unsigned skeys[512 * 8];
  const int n_steps = __builtin_amdgcn_readfirstlane(nsteps_p[0]);
  const int nfill = n_steps < 512 ? n_steps : 512;
  for (int l = (int)threadIdx.x; l < nfill; l += (int)blockDim.x) {
    unsigned o0, o1;
    tf2x32(0u, 1u, 0u, (unsigned)l, o0, o1);
    const unsigned k2 = o0 ^ o1 ^ 0x1BD11BDAu;
    unsigned* wp = &skeys[8 * l];
    wp[0] = o0;       wp[1] = o1;       wp[2] = k2;       wp[3] = k2 + 1u;
    wp[4] = o0 + 2u;  wp[5] = o1 + 3u;  wp[6] = k2 + 4u;  wp[7] = o0 + 5u;
  }
  __syncthreads();

  const int j = (int)(blockIdx.x * blockDim.x + threadIdx.x);
  if (j >= N) return;
  const unsigned cj = (unsigned)j;
  float x = x0p[j];
  const float b = bias[j % ndim];

  if (n_steps <= 512) {
    int t = 0;
#pragma unroll 1
    for (; t + 1 < n_steps; t += 2) {
      unsigned wa[8], wb[8];
      *(uint4*)&wa[0] = *(const uint4*)&skeys[8 * t];
      *(uint4*)&wa[4] = *(const uint4*)&skeys[8 * t + 4];
      *(uint4*)&wb[0] = *(const uint4*)&skeys[8 * t + 8];
      *(uint4*)&wb[4] = *(const uint4*)&skeys[8 * t + 12];
      const unsigned ra = tf_fold(wa, cj);   // step t   (independent chain)
      const unsigned rb = tf_fold(wb, cj);   // step t+1 (independent chain)
      const float na = bits_to_normal(ra);
      const float nb = bits_to_normal(rb);
      // grad = 2*J2*x + 4*J4*x^3 + b = -2x + ((2x)*x)*x + b (ref assoc order)
      float g = -2.0f * x + ((2.0f * x) * x) * x + b;
      x = (x - g * 0.01f) + na * 0.1f;
      g = -2.0f * x + ((2.0f * x) * x) * x + b;
      x = (x - g * 0.01f) + nb * 0.1f;
    }
    if (t < n_steps) {  // odd-step tail
      unsigned wa[8];
      *(uint4*)&wa[0] = *(const uint4*)&skeys[8 * t];
      *(uint4*)&wa[4] = *(const uint4*)&skeys[8 * t + 4];
      const float na = bits_to_normal(tf_fold(wa, cj));
      const float g = -2.0f * x + ((2.0f * x) * x) * x + b;
      x = (x - g * 0.01f) + na * 0.1f;
    }
  } else {
    // Fallback for n_steps > 512: recompute step key inline.
    for (int t = 0; t < n_steps; ++t) {
      unsigned o0, o1, r0, r1;
      tf2x32(0u, 1u, 0u, (unsigned)t, o0, o1);
      tf2x32(o0, o1, 0u, cj, r0, r1);
      const float nz = bits_to_normal(r0 ^ r1);
      const float g = -2.0f * x + ((2.0f * x) * x) * x + b;
      x = (x - g * 0.01f) + nz * 0.1f;
    }
  }
  out[j] = x;
}

extern "C" void kernel_launch(void* const* d_in, const int* in_sizes, int n_in,
                              void* d_out, int out_size, void* d_ws, size_t ws_size,
                              hipStream_t stream) {
  (void)n_in; (void)d_ws; (void)ws_size; (void)out_size;
  const float* x0 = (const float*)d_in[0];
  const float* b = (const float*)d_in[1];
  const int* ns = (const int*)d_in[2];
  float* out = (float*)d_out;

  const int n = in_sizes[0];     // 2048*256 = 524288
  const int ndim = in_sizes[1];  // 256
  const int block = 256;
  const int grid = (n + block - 1) / block;  // 2048 blocks -> 8/CU, 32 waves/CU
  hipLaunchKernelGGL(langevin_tf, dim3(grid), dim3(block), 0, stream,
                     x0, b, ns, out, n, ndim);
}